// Round 10
// baseline (357.475 us; speedup 1.0000x reference)
//
#include <hip/hip_runtime.h>
#include <hip/hip_fp16.h>
#include <math.h>

// Problem constants (from reference)
#define LL   2048     // seq len
#define BB   64       // batch
#define EE   256      // embedding
#define HH   128      // lstm hidden per dir
#define GG   512      // 4*H gates
#define TT   128      // utterances (L / SEP_EVERY)
#define SEPT 50256

// ---------------------------------------------------------------------------
// Kernel 1: per-column prefix-scan of SEP flags -> seg[t,b], plus per-(utt,b)
// token counts and start offsets (segments are contiguous per column).
// ---------------------------------------------------------------------------
__global__ __launch_bounds__(256) void segscan_k(
    const int* __restrict__ x, int* __restrict__ seg,
    int* __restrict__ cnt, int* __restrict__ start)
{
    int b   = blockIdx.x;    // 0..63
    int tid = threadIdx.x;   // 0..255, 8 tokens each
    __shared__ int tsum[256];
    __shared__ int ucnt[TT];
    __shared__ int ustart[TT];

    int flags[8];
    int local = 0;
#pragma unroll
    for (int i = 0; i < 8; i++) {
        int t = tid * 8 + i;
        flags[i] = (x[t * BB + b] == SEPT) ? 1 : 0;
        local += flags[i];
    }
    tsum[tid] = local;
    __syncthreads();
    int val = local;
    for (int off = 1; off < 256; off <<= 1) {
        int other = (tid >= off) ? tsum[tid - off] : 0;
        __syncthreads();
        val += other;
        tsum[tid] = val;
        __syncthreads();
    }
    int excl = val - local;   // seps strictly before this thread's chunk

    if (tid < TT) ucnt[tid] = 0;
    __syncthreads();
    int run = excl;
#pragma unroll
    for (int i = 0; i < 8; i++) {
        int t = tid * 8 + i;
        int s = run;                 // seg id = #seps before this token
        seg[t * BB + b] = s;
        run += flags[i];
        if (s < TT) atomicAdd(&ucnt[s], 1);
    }
    __syncthreads();
    if (tid == 0) {
        int acc = 0;
        for (int u = 0; u < TT; u++) { ustart[u] = acc; acc += ucnt[u]; }
    }
    __syncthreads();
    if (tid < TT) {
        cnt[tid * BB + b]   = ucnt[tid];
        start[tid * BB + b] = ustart[tid];
    }
}

// ---------------------------------------------------------------------------
// Kernel 2: embedding gather + mean pool. One WAVE per (utt,b); lane holds a
// float4 column slice -> one coalesced 1KB row read per token. Grid = 2048.
// ---------------------------------------------------------------------------
__global__ __launch_bounds__(256) void pool_k(
    const int* __restrict__ x, const float* __restrict__ emb,
    const int* __restrict__ cnt, const int* __restrict__ start,
    float* __restrict__ up)
{
    int wid  = threadIdx.x >> 6;
    int lane = threadIdx.x & 63;
    int bid  = blockIdx.x * 4 + wid;   // u*64+b, bid in [0,8192)
    int b    = bid & 63;
    int c    = cnt[bid];
    int st   = start[bid];

    float4 acc = {0.f, 0.f, 0.f, 0.f};
    int tok = (c > 0) ? x[st * BB + b] : 0;
    for (int j = 0; j < c; j++) {
        int tok_n = (j + 1 < c) ? x[(st + j + 1) * BB + b] : 0;  // prefetch
        float4 v = ((const float4*)(emb + (size_t)tok * EE))[lane];
        acc.x += v.x; acc.y += v.y; acc.z += v.z; acc.w += v.w;
        tok = tok_n;
    }
    float inv = (c > 0) ? 1.f / (float)c : 0.f;
    float4 r = {acc.x * inv, acc.y * inv, acc.z * inv, acc.w * inv};
    ((float4*)(up + (size_t)bid * EE))[lane] = r;
}

// ---------------------------------------------------------------------------
// Kernel 3: xp = u @ W_cat^T + (b_ih + b_hh).  fp32 register-tiled GEMM, v2.
// 128x128 tile, 256 threads, 8x8 micro-tile. Grid (64, 8) = 512 blocks.
// ---------------------------------------------------------------------------
__global__ __launch_bounds__(256) void xp_gemm_k(
    const float* __restrict__ A,
    const float* __restrict__ wf, const float* __restrict__ wb,
    const float* __restrict__ bihf, const float* __restrict__ bhhf,
    const float* __restrict__ bihb, const float* __restrict__ bhhb,
    float* __restrict__ C)
{
    __shared__ float As[32][128];   // [k][m] 16 KB
    __shared__ float Bs[32][128];   // [k][n] 16 KB
    int tid  = threadIdx.x;
    int row0 = blockIdx.x * 128;    // 64 blocks
    int col0 = blockIdx.y * 128;    // 8 blocks
    int tx = tid & 15, ty = tid >> 4;   // 16 x 16 threads, 8x8 micro
    float acc[8][8] = {};

    for (int k0 = 0; k0 < EE; k0 += 32) {
#pragma unroll
        for (int i = 0; i < 4; i++) {
            int idx = tid + i * 256;       // float4 slot, 1024 total
            int m   = idx >> 3;            // 0..127
            int k4  = idx & 7;             // 0..7
            float4 av = *(const float4*)(A + (size_t)(row0 + m) * EE + k0 + k4 * 4);
            As[k4 * 4 + 0][m] = av.x; As[k4 * 4 + 1][m] = av.y;
            As[k4 * 4 + 2][m] = av.z; As[k4 * 4 + 3][m] = av.w;
        }
#pragma unroll
        for (int i = 0; i < 4; i++) {
            int idx = tid + i * 256;
            int n   = idx >> 3;
            int k4  = idx & 7;
            int gc  = col0 + n;
            const float* wsrc = (gc < GG) ? (wf + (size_t)gc * EE)
                                          : (wb + (size_t)(gc - GG) * EE);
            float4 bv = *(const float4*)(wsrc + k0 + k4 * 4);
            Bs[k4 * 4 + 0][n] = bv.x; Bs[k4 * 4 + 1][n] = bv.y;
            Bs[k4 * 4 + 2][n] = bv.z; Bs[k4 * 4 + 3][n] = bv.w;
        }
        __syncthreads();
#pragma unroll
        for (int k = 0; k < 32; k++) {
            float a8[8], b8[8];
            *(float4*)&a8[0] = *(const float4*)&As[k][ty * 8 + 0];
            *(float4*)&a8[4] = *(const float4*)&As[k][ty * 8 + 4];
            *(float4*)&b8[0] = *(const float4*)&Bs[k][tx * 8 + 0];
            *(float4*)&b8[4] = *(const float4*)&Bs[k][tx * 8 + 4];
#pragma unroll
            for (int i = 0; i < 8; i++)
#pragma unroll
                for (int j = 0; j < 8; j++)
                    acc[i][j] += a8[i] * b8[j];
        }
        __syncthreads();
    }

    // epilogue: bias + float4 stores
    float bias[8];
#pragma unroll
    for (int j = 0; j < 8; j++) {
        int gc = col0 + tx * 8 + j;
        bias[j] = (gc < GG) ? (bihf[gc] + bhhf[gc])
                            : (bihb[gc - GG] + bhhb[gc - GG]);
    }
#pragma unroll
    for (int i = 0; i < 8; i++) {
        int r = row0 + ty * 8 + i;
        float4 v0 = {acc[i][0] + bias[0], acc[i][1] + bias[1],
                     acc[i][2] + bias[2], acc[i][3] + bias[3]};
        float4 v1 = {acc[i][4] + bias[4], acc[i][5] + bias[5],
                     acc[i][6] + bias[6], acc[i][7] + bias[7]};
        *(float4*)(C + (size_t)r * 1024 + col0 + tx * 8 + 0) = v0;
        *(float4*)(C + (size_t)r * 1024 + col0 + tx * 8 + 4) = v1;
    }
}

// ---------------------------------------------------------------------------
// Fast activations
// ---------------------------------------------------------------------------
__device__ __forceinline__ float sigm_f(float x) {
    return 1.f / (1.f + __expf(-x));
}
__device__ __forceinline__ float tanh_f(float x) {
    return 1.f - 2.f / (__expf(2.f * x) + 1.f);
}

// ---------------------------------------------------------------------------
// Kernel 3.5: convert W_hh (both dirs) to fp16, PERMUTED for coalesced
// wave-streaming: out[dir][wv][j][lane][k] <- whh[dir][(lane+64j)][16wv+k].
// ---------------------------------------------------------------------------
__global__ __launch_bounds__(256) void cvt_k(
    const float* __restrict__ wf, const float* __restrict__ wb,
    __half* __restrict__ o)
{
    int i = blockIdx.x * 256 + threadIdx.x;   // 0..131071
    int k   = i & 15;
    int l   = (i >> 4) & 63;
    int j   = (i >> 10) & 7;
    int wv  = (i >> 13) & 7;
    int dir = i >> 16;
    const float* src = dir ? wb : wf;
    o[i] = __float2half(src[(l + 64 * j) * HH + 16 * wv + k]);
}

// v_dot2_f32_f16: c += a.x*b.x + a.y*b.y, fp16 inputs, fp32 accumulate.
typedef _Float16 h2v __attribute__((ext_vector_type(2)));
__device__ __forceinline__ float dot2h(unsigned wbits, unsigned hbits, float c) {
    return __builtin_amdgcn_fdot2(__builtin_bit_cast(h2v, wbits),
                                  __builtin_bit_cast(h2v, hbits), c, false);
}

// ---------------------------------------------------------------------------
// Kernel 4: LSTM recurrence — r21: asm-PINNED load issue + counted wait
// (HipKittens T3/T4 pattern, the one untried combination).
//
// Triangulation r17-r20: dur ~110-117 us is insensitive to VALU count
// (fp16 cvt+fma 30% -> dot2 19% VALUBusy), to feed bytes (fp32->fp16),
// to port split (LDS+L2), and to drain batching (r20 neutral). The
// remaining consistent explanation: the 10 per-thread L2 weight loads are
// scheduled ~2-3 in flight (RA sinks plain loads; VGPR stuck ~52) -> ~4
// serialized L2 round trips ~800 cyc/step, suffered by all 8 symmetric
// waves at once. Every variant since r2 shares this.
//
// Prior asm attempts differed: r12-16 held asm loads across the WHOLE loop
// (live range = kernel -> RA spilled); r18 made the FMAs asm (forfeited
// pipelining). r21: asm volatile pins only the ISSUE of the 10 loads at
// the top of p1 (asm volatile ops keep mutual order; sched_barrier stops
// sinking); results live only ~30 insts until the q-dot section (no
// loop-carried pressure). LDS dots (j=0..2) + h-read run under the single
// L2 round trip; then s_waitcnt vmcnt(0) + sched_barrier(0) (rule #18)
// gates the q dots.
// Predicted: step ~1000-1400 cyc; lstm 113 -> 55-75 us; VGPR 85-105.
// Fail tell: VGPR ~52 & dur ~113 -> RA spilled short-range asm outputs too
// -> lstm plateaued at toolchain level; pivot to xp_gemm/pool.
// ---------------------------------------------------------------------------
__global__ __launch_bounds__(512, 2) void lstm_rec_k(
    const float* __restrict__ xp,            // [T*B][1024]
    const __half* __restrict__ wh16,         // [2][wv][j][lane][k] permuted
    float* __restrict__ hout)                // [2][T][B][H]
{
    int bid = blockIdx.x;
    int dir = bid >> 6;
    int b   = bid & 63;
    int tid = threadIdx.x;
    int wv  = tid >> 6;      // wave id 0..7 -> k-slice
    int l   = tid & 63;      // lane -> gate set {l + 64j}
    const __half* wh = wh16 + (size_t)dir * (GG * HH);
    // per-gate contiguous 16-half rows: base of (wv, j=0, l)
    const __half* wbase = wh + (((size_t)wv * 8) * 64 + l) * 16;

    // LDS: staged weights for j=0..2, layout [wv*3+jj][hf][l][k8].
    __shared__ __align__(16) __half ldsW[24576];   // 48 KB
    __shared__ __align__(16) __half h16_lds[HH];   // h as fp16 (recurrence input)
    __shared__ float part[GG][9];   // [gate][wave], pad 9 -> 0 conflicts (r2)
    __shared__ float act[GG];

    // ---- one-time stage: 48 KB, 96 B/thread ----
#pragma unroll
    for (int t = 0; t < 6; t++) {
        int cc  = tid + t * 512;            // 0..3071 = ((wv*3+jj)*2+hf)*64 + l
        int l2  = cc & 63;
        int hf  = (cc >> 6) & 1;
        int rem = cc >> 7;                  // 0..23
        int jj  = rem % 3;
        int wv2 = rem / 3;
        const __half* src = wh + (((size_t)(wv2 * 8 + jj) * 64 + l2) * 16 + hf * 8);
        *(uint4*)(ldsW + (size_t)cc * 8) = *(const uint4*)src;
    }

    int g    = tid;                 // gate this thread reduces in phase 2
    int sect = g >> 7;              // 0:i 1:f 2:g 3:o (wave-uniform)

    float c = 0.f;                  // cell state (threads < 128)
    if (tid < HH) h16_lds[tid] = __float2half(0.f);
    __syncthreads();

    const uint4* ldsW4 = (const uint4*)ldsW;
    const uint4* h16v  = (const uint4*)h16_lds;

    int t0   = dir ? (TT - 1) : 0;
    float xg = xp[(size_t)(t0 * BB + b) * 1024 + dir * GG + g];

    for (int s = 0; s < TT; s++) {
        // ---- phase 1 ----
        // (a) asm-pinned issue of ALL 10 streamed weight loads (j=3..7):
        //     one L2 round trip, covered by the LDS work below.
        uint4 q[10];
#pragma unroll
        for (int j = 0; j < 5; j++) {
            const __half* pj = wbase + (size_t)(j + 3) * 1024;
            asm volatile("global_load_dwordx4 %0, %1, off"
                         : "=v"(q[j * 2 + 0]) : "v"(pj) : "memory");
            asm volatile("global_load_dwordx4 %0, %1, off offset:16"
                         : "=v"(q[j * 2 + 1]) : "v"(pj) : "memory");
        }
        __builtin_amdgcn_sched_barrier(0);

        // (b) h broadcast (same-address, conflict-free) + LDS dots j=0..2
        unsigned hhv[8];
        {
            uint4 ha  = h16v[wv * 2 + 0];   // halves 16wv..16wv+7
            uint4 hbq = h16v[wv * 2 + 1];   // halves 16wv+8..16wv+15
            hhv[0] = ha.x;  hhv[1] = ha.y;  hhv[2] = ha.z;  hhv[3] = ha.w;
            hhv[4] = hbq.x; hhv[5] = hbq.y; hhv[6] = hbq.z; hhv[7] = hbq.w;
        }

        float acc[8] = {0.f, 0.f, 0.f, 0.f, 0.f, 0.f, 0.f, 0.f};
#pragma unroll
        for (int jj = 0; jj < 3; jj++) {
            uint4 w0 = ldsW4[((wv * 3 + jj) * 2 + 0) * 64 + l];   // k 0..7
            uint4 w1 = ldsW4[((wv * 3 + jj) * 2 + 1) * 64 + l];   // k 8..15
            acc[jj] = dot2h(w0.x, hhv[0], acc[jj]);
            acc[jj] = dot2h(w0.y, hhv[1], acc[jj]);
            acc[jj] = dot2h(w0.z, hhv[2], acc[jj]);
            acc[jj] = dot2h(w0.w, hhv[3], acc[jj]);
            acc[jj] = dot2h(w1.x, hhv[4], acc[jj]);
            acc[jj] = dot2h(w1.y, hhv[5], acc[jj]);
            acc[jj] = dot2h(w1.z, hhv[6], acc[jj]);
            acc[jj] = dot2h(w1.w, hhv[7], acc[jj]);
        }

        // (c) gate the streamed dots on load completion (rule #18 fence)
        asm volatile("s_waitcnt vmcnt(0)" ::: "memory");
        __builtin_amdgcn_sched_barrier(0);

#pragma unroll
        for (int j = 0; j < 5; j++) {
            uint4 q0 = q[j * 2 + 0];
            uint4 q1 = q[j * 2 + 1];
            acc[j + 3] = dot2h(q0.x, hhv[0], acc[j + 3]);
            acc[j + 3] = dot2h(q0.y, hhv[1], acc[j + 3]);
            acc[j + 3] = dot2h(q0.z, hhv[2], acc[j + 3]);
            acc[j + 3] = dot2h(q0.w, hhv[3], acc[j + 3]);
            acc[j + 3] = dot2h(q1.x, hhv[4], acc[j + 3]);
            acc[j + 3] = dot2h(q1.y, hhv[5], acc[j + 3]);
            acc[j + 3] = dot2h(q1.z, hhv[6], acc[j + 3]);
            acc[j + 3] = dot2h(q1.w, hhv[7], acc[j + 3]);
        }

        // prefetch next step's xp while dots drain
        float xg_next = xg;
        if (s < TT - 1) {
            int tn = dir ? (TT - 2 - s) : (s + 1);
            xg_next = xp[(size_t)(tn * BB + b) * 1024 + dir * GG + g];
        }

#pragma unroll
        for (int j = 0; j < 8; j++)
            part[l + 64 * j][wv] = acc[j];
        __syncthreads();

        // ---- phase 2: reduce partials for gate g, activate ----
        float sum = xg;
#pragma unroll
        for (int w2 = 0; w2 < 8; w2++)
            sum += part[g][w2];
        act[g] = (sect == 2) ? tanh_f(sum) : sigm_f(sum);
        __syncthreads();

        // ---- phase 3: c/h update for hidden unit tid (<128) ----
        if (tid < HH) {
            float si = act[tid], sf = act[HH + tid];
            float tg = act[2 * HH + tid], so = act[3 * HH + tid];
            c = sf * c + si * tg;
            float h = so * tanh_f(c);
            h16_lds[tid] = __float2half(h);   // recurrence input (fp16)
            int t = dir ? (TT - 1 - s) : s;
            hout[((size_t)(dir * TT + t) * BB + b) * HH + tid] = h;  // fp32 out
        }
        xg = xg_next;
        __syncthreads();   // h16 write (p3) vs next p1 read; part rewrite vs p2
    }
}

// ---------------------------------------------------------------------------
// Kernel 5: head — logits, softmax, argmax, chosen policy. One wave per row.
// ---------------------------------------------------------------------------
__global__ __launch_bounds__(256) void head_k(
    const float* __restrict__ hbuf,           // [2][T][B][H]
    const float* __restrict__ wout, const float* __restrict__ bout,
    float* __restrict__ out)
{
    int wid  = threadIdx.x >> 6;
    int lane = threadIdx.x & 63;
    int row  = blockIdx.x * 4 + wid;          // t*64+b, 0..8191
    int t = row >> 6, b = row & 63;
    const float* hf = hbuf + ((size_t)(t)      * BB + b) * HH;
    const float* hb = hbuf + ((size_t)(TT + t) * BB + b) * HH;

    float l0 = 0.f, l1 = 0.f, v;
    v = hf[lane];      l0 += v * wout[lane];           l1 += v * wout[256 + lane];
    v = hf[lane + 64]; l0 += v * wout[64 + lane];      l1 += v * wout[320 + lane];
    v = hb[lane];      l0 += v * wout[128 + lane];     l1 += v * wout[384 + lane];
    v = hb[lane + 64]; l0 += v * wout[192 + lane];     l1 += v * wout[448 + lane];
#pragma unroll
    for (int off = 32; off > 0; off >>= 1) {
        l0 += __shfl_down(l0, off);
        l1 += __shfl_down(l1, off);
    }
    if (lane == 0) {
        l0 += bout[0]; l1 += bout[1];
        float m  = fmaxf(l0, l1);
        float e0 = __expf(l0 - m), e1 = __expf(l1 - m);
        float inv = 1.f / (e0 + e1);
        float p0 = e0 * inv, p1 = e1 * inv;
        int amax = (l1 > l0) ? 1 : 0;          // tie -> 0, matches jnp.argmax
        out[(size_t)row * 2 + 0] = l0;
        out[(size_t)row * 2 + 1] = l1;
        out[16384 + (size_t)row * 2 + 0] = p0;
        out[16384 + (size_t)row * 2 + 1] = p1;
        out[32768 + row] = amax ? p1 : p0;
        out[40960 + row] = (float)amax;
    }
}

// ---------------------------------------------------------------------------
// Kernel 6: expand utterance mask to tokens, write masked input as float.
// ---------------------------------------------------------------------------
__global__ __launch_bounds__(256) void mask_k(
    const int* __restrict__ x, const int* __restrict__ seg,
    const float* __restrict__ umask, float* __restrict__ out4)
{
    int idx = blockIdx.x * 256 + threadIdx.x;    // < 131072
    int b = idx & 63;
    int s = seg[idx];
    if (s > TT - 1) s = TT - 1;                  // jnp OOB indexing clamps
    if (s < 0) s = 0;
    float keep = umask[s * BB + b];
    out4[idx] = (keep != 0.f) ? (float)x[idx] : 0.f;
}

// ---------------------------------------------------------------------------
extern "C" void kernel_launch(void* const* d_in, const int* in_sizes, int n_in,
                              void* d_out, int out_size, void* d_ws, size_t ws_size,
                              hipStream_t stream)
{
    const int*   x    = (const int*)  d_in[0];
    const float* emb  = (const float*)d_in[1];
    const float* wihf = (const float*)d_in[2];
    const float* whhf = (const float*)d_in[3];
    const float* bihf = (const float*)d_in[4];
    const float* bhhf = (const float*)d_in[5];
    const float* wihb = (const float*)d_in[6];
    const float* whhb = (const float*)d_in[7];
    const float* bihb = (const float*)d_in[8];
    const float* bhhb = (const float*)d_in[9];
    const float* wout = (const float*)d_in[10];
    const float* bout = (const float*)d_in[11];
    float* out = (float*)d_out;
    char*  ws  = (char*)d_ws;

    // workspace layout (bytes)
    int*   seg   = (int*)  (ws + 0);         // 2048*64*4   = 524288
    int*   cnt   = (int*)  (ws + 524288);    // 128*64*4    = 32768
    int*   start = (int*)  (ws + 557056);    // 32768
    float* up    = (float*)(ws + 589824);    // 128*64*256*4  = 8 MB
    float* xp    = (float*)(ws + 8978432);   // 128*64*1024*4 = 32 MB
    float* hbuf  = (float*)(ws + 42532864);  // 2*128*64*128*4 = 8 MB
    // fp16 weight copy lives in the first 256 KB of `up`, which is dead
    // after xp_gemm_k reads it (pool_k regenerates up each iteration).
    __half* wh16 = (__half*)up;

    segscan_k<<<64, 256, 0, stream>>>(x, seg, cnt, start);
    pool_k<<<2048, 256, 0, stream>>>(x, emb, cnt, start, up);   // 8192 waves
    xp_gemm_k<<<dim3(64, 8), 256, 0, stream>>>(up, wihf, wihb, bihf, bhhf, bihb, bhhb, xp);
    cvt_k<<<512, 256, 0, stream>>>(whhf, whhb, wh16);
    lstm_rec_k<<<128, 512, 0, stream>>>(xp, wh16, hbuf);
    head_k<<<2048, 256, 0, stream>>>(hbuf, wout, bout, out);
    mask_k<<<512, 256, 0, stream>>>(x, seg, out + 40960, out + 49152);
}

// Round 11
// 288.147 us; speedup vs baseline: 1.2406x; 1.2406x over previous
//
#include <hip/hip_runtime.h>
#include <hip/hip_fp16.h>
#include <math.h>

// Problem constants (from reference)
#define LL   2048     // seq len
#define BB   64       // batch
#define EE   256      // embedding
#define HH   128      // lstm hidden per dir
#define GG   512      // 4*H gates
#define TT   128      // utterances (L / SEP_EVERY)
#define SEPT 50256

// ---------------------------------------------------------------------------
// Kernel 1: per-column prefix-scan of SEP flags -> seg[t,b], plus per-(utt,b)
// token counts and start offsets (segments are contiguous per column).
// ---------------------------------------------------------------------------
__global__ __launch_bounds__(256) void segscan_k(
    const int* __restrict__ x, int* __restrict__ seg,
    int* __restrict__ cnt, int* __restrict__ start)
{
    int b   = blockIdx.x;    // 0..63
    int tid = threadIdx.x;   // 0..255, 8 tokens each
    __shared__ int tsum[256];
    __shared__ int ucnt[TT];
    __shared__ int ustart[TT];

    int flags[8];
    int local = 0;
#pragma unroll
    for (int i = 0; i < 8; i++) {
        int t = tid * 8 + i;
        flags[i] = (x[t * BB + b] == SEPT) ? 1 : 0;
        local += flags[i];
    }
    tsum[tid] = local;
    __syncthreads();
    int val = local;
    for (int off = 1; off < 256; off <<= 1) {
        int other = (tid >= off) ? tsum[tid - off] : 0;
        __syncthreads();
        val += other;
        tsum[tid] = val;
        __syncthreads();
    }
    int excl = val - local;   // seps strictly before this thread's chunk

    if (tid < TT) ucnt[tid] = 0;
    __syncthreads();
    int run = excl;
#pragma unroll
    for (int i = 0; i < 8; i++) {
        int t = tid * 8 + i;
        int s = run;                 // seg id = #seps before this token
        seg[t * BB + b] = s;
        run += flags[i];
        if (s < TT) atomicAdd(&ucnt[s], 1);
    }
    __syncthreads();
    if (tid == 0) {
        int acc = 0;
        for (int u = 0; u < TT; u++) { ustart[u] = acc; acc += ucnt[u]; }
    }
    __syncthreads();
    if (tid < TT) {
        cnt[tid * BB + b]   = ucnt[tid];
        start[tid * BB + b] = ustart[tid];
    }
}

// ---------------------------------------------------------------------------
// Kernel 2: embedding gather + mean pool. One WAVE per (utt,b); lane holds a
// float4 column slice -> one coalesced 1KB row read per token. Grid = 2048.
// ---------------------------------------------------------------------------
__global__ __launch_bounds__(256) void pool_k(
    const int* __restrict__ x, const float* __restrict__ emb,
    const int* __restrict__ cnt, const int* __restrict__ start,
    float* __restrict__ up)
{
    int wid  = threadIdx.x >> 6;
    int lane = threadIdx.x & 63;
    int bid  = blockIdx.x * 4 + wid;   // u*64+b, bid in [0,8192)
    int b    = bid & 63;
    int c    = cnt[bid];
    int st   = start[bid];

    float4 acc = {0.f, 0.f, 0.f, 0.f};
    int tok = (c > 0) ? x[st * BB + b] : 0;
    for (int j = 0; j < c; j++) {
        int tok_n = (j + 1 < c) ? x[(st + j + 1) * BB + b] : 0;  // prefetch
        float4 v = ((const float4*)(emb + (size_t)tok * EE))[lane];
        acc.x += v.x; acc.y += v.y; acc.z += v.z; acc.w += v.w;
        tok = tok_n;
    }
    float inv = (c > 0) ? 1.f / (float)c : 0.f;
    float4 r = {acc.x * inv, acc.y * inv, acc.z * inv, acc.w * inv};
    ((float4*)(up + (size_t)bid * EE))[lane] = r;
}

// ---------------------------------------------------------------------------
// Kernel 3: xp = u @ W_cat^T + (b_ih + b_hh).  fp32 register-tiled GEMM, v2.
// 128x128 tile, 256 threads, 8x8 micro-tile. Grid (64, 8) = 512 blocks.
// ---------------------------------------------------------------------------
__global__ __launch_bounds__(256) void xp_gemm_k(
    const float* __restrict__ A,
    const float* __restrict__ wf, const float* __restrict__ wb,
    const float* __restrict__ bihf, const float* __restrict__ bhhf,
    const float* __restrict__ bihb, const float* __restrict__ bhhb,
    float* __restrict__ C)
{
    __shared__ float As[32][128];   // [k][m] 16 KB
    __shared__ float Bs[32][128];   // [k][n] 16 KB
    int tid  = threadIdx.x;
    int row0 = blockIdx.x * 128;    // 64 blocks
    int col0 = blockIdx.y * 128;    // 8 blocks
    int tx = tid & 15, ty = tid >> 4;   // 16 x 16 threads, 8x8 micro
    float acc[8][8] = {};

    for (int k0 = 0; k0 < EE; k0 += 32) {
#pragma unroll
        for (int i = 0; i < 4; i++) {
            int idx = tid + i * 256;       // float4 slot, 1024 total
            int m   = idx >> 3;            // 0..127
            int k4  = idx & 7;             // 0..7
            float4 av = *(const float4*)(A + (size_t)(row0 + m) * EE + k0 + k4 * 4);
            As[k4 * 4 + 0][m] = av.x; As[k4 * 4 + 1][m] = av.y;
            As[k4 * 4 + 2][m] = av.z; As[k4 * 4 + 3][m] = av.w;
        }
#pragma unroll
        for (int i = 0; i < 4; i++) {
            int idx = tid + i * 256;
            int n   = idx >> 3;
            int k4  = idx & 7;
            int gc  = col0 + n;
            const float* wsrc = (gc < GG) ? (wf + (size_t)gc * EE)
                                          : (wb + (size_t)(gc - GG) * EE);
            float4 bv = *(const float4*)(wsrc + k0 + k4 * 4);
            Bs[k4 * 4 + 0][n] = bv.x; Bs[k4 * 4 + 1][n] = bv.y;
            Bs[k4 * 4 + 2][n] = bv.z; Bs[k4 * 4 + 3][n] = bv.w;
        }
        __syncthreads();
#pragma unroll
        for (int k = 0; k < 32; k++) {
            float a8[8], b8[8];
            *(float4*)&a8[0] = *(const float4*)&As[k][ty * 8 + 0];
            *(float4*)&a8[4] = *(const float4*)&As[k][ty * 8 + 4];
            *(float4*)&b8[0] = *(const float4*)&Bs[k][tx * 8 + 0];
            *(float4*)&b8[4] = *(const float4*)&Bs[k][tx * 8 + 4];
#pragma unroll
            for (int i = 0; i < 8; i++)
#pragma unroll
                for (int j = 0; j < 8; j++)
                    acc[i][j] += a8[i] * b8[j];
        }
        __syncthreads();
    }

    // epilogue: bias + float4 stores
    float bias[8];
#pragma unroll
    for (int j = 0; j < 8; j++) {
        int gc = col0 + tx * 8 + j;
        bias[j] = (gc < GG) ? (bihf[gc] + bhhf[gc])
                            : (bihb[gc - GG] + bhhb[gc - GG]);
    }
#pragma unroll
    for (int i = 0; i < 8; i++) {
        int r = row0 + ty * 8 + i;
        float4 v0 = {acc[i][0] + bias[0], acc[i][1] + bias[1],
                     acc[i][2] + bias[2], acc[i][3] + bias[3]};
        float4 v1 = {acc[i][4] + bias[4], acc[i][5] + bias[5],
                     acc[i][6] + bias[6], acc[i][7] + bias[7]};
        *(float4*)(C + (size_t)r * 1024 + col0 + tx * 8 + 0) = v0;
        *(float4*)(C + (size_t)r * 1024 + col0 + tx * 8 + 4) = v1;
    }
}

// ---------------------------------------------------------------------------
// Fast activations
// ---------------------------------------------------------------------------
__device__ __forceinline__ float sigm_f(float x) {
    return 1.f / (1.f + __expf(-x));
}
__device__ __forceinline__ float tanh_f(float x) {
    return 1.f - 2.f / (__expf(2.f * x) + 1.f);
}

// ---------------------------------------------------------------------------
// Kernel 3.5: convert W_hh (both dirs) to fp16 in octet-major layout:
// o[((dir*16+q)*512+g)*8+e] = whh[dir][g][q*8+e]   (q = k-octet 0..15)
// At step time, all 512 threads (one gate each) read octet q: 16 B/lane,
// lanes = consecutive gates -> fully coalesced 1KB/wave per load.
// ---------------------------------------------------------------------------
__global__ __launch_bounds__(256) void cvt_k(
    const float* __restrict__ wf, const float* __restrict__ wb,
    __half* __restrict__ o)
{
    int i = blockIdx.x * 256 + threadIdx.x;   // 0..131071
    int e   = i & 7;
    int g   = (i >> 3) & 511;
    int q   = (i >> 12) & 15;
    int dir = i >> 16;
    const float* src = dir ? wb : wf;
    o[i] = __float2half(src[(size_t)g * HH + q * 8 + e]);
}

// v_dot2_f32_f16: c += a.x*b.x + a.y*b.y, fp16 inputs, fp32 accumulate.
typedef _Float16 h2v __attribute__((ext_vector_type(2)));
__device__ __forceinline__ float dot2h(unsigned wbits, unsigned hbits, float c) {
    return __builtin_amdgcn_fdot2(__builtin_bit_cast(h2v, wbits),
                                  __builtin_bit_cast(h2v, hbits), c, false);
}

// ---------------------------------------------------------------------------
// Kernel 4: LSTM recurrence — r22: ONE GATE PER THREAD, phase-2 ELIMINATED.
//
// r12-r21 verdict: every scheduling-control attempt (asm pins, occupancy
// attrs, preloads, hand-asm FMA) was defeated or inverted by the RA; only
// plain compiler-scheduled HIP performs (r17: 108 us). The remaining lever
// is STRUCTURE: r2's 3-phase shape pays a cross-wave LDS reduction
// (part[] write + 8 reads + extra barrier + act round-trip ~500-700 cyc
// serial latency) purely because each thread computed 8 gates x 16 k.
//
// r22: 512 threads = 512 gates; each thread computes its gate's FULL
// 128-k dot (64 dot2), so the pre-activation finishes in-register:
// activate inline, write act[g], ONE barrier, p3, barrier. part[] gone.
// Feed split across ports: k-octets 0..7 staged once in LDS (64 KB,
// linear conflict-free), octets 8..15 streamed coalesced from L2
// (64 KB/step/CU ~= 530 cyc, HALF of r17's stream), concurrent.
// Sum order: acc = xg, then k-ascending — same class as r17 (0.00195).
// Predicted: step 2030 -> 1100-1400 cyc; lstm 108 -> 60-80 us.
// Pre-commit: dur >= 100 us => lstm is at its structural floor; pivot.
// ---------------------------------------------------------------------------
__global__ __launch_bounds__(512, 2) void lstm_rec_k(
    const float* __restrict__ xp,            // [T*B][1024]
    const __half* __restrict__ w16,          // [dir][q][gate][8] octet-major
    float* __restrict__ hout)                // [2][T][B][H]
{
    int bid = blockIdx.x;
    int dir = bid >> 6;
    int b   = bid & 63;
    int tid = threadIdx.x;
    int g   = tid;                  // this thread's gate
    int sect = g >> 7;              // 0:i 1:f 2:g 3:o (wave-uniform)
    const uint4* wp = (const uint4*)(w16 + (size_t)dir * (16 * GG * 8));

    __shared__ uint4 wlds[8 * GG];            // octets 0..7, 64 KB, [q][g]
    __shared__ __align__(16) __half h16_lds[HH];
    __shared__ float act[GG];

    // one-time stage: 64 KB (coalesced: consecutive tids -> consecutive uint4)
#pragma unroll
    for (int t = 0; t < 8; t++) {
        int idx = tid + t * 512;    // = q*512 + g for q=0..7
        wlds[idx] = wp[idx];
    }

    float c = 0.f;                  // cell state (threads < 128)
    if (tid < HH) h16_lds[tid] = __float2half(0.f);
    __syncthreads();

    const uint4* h16v = (const uint4*)h16_lds;   // 16 octets of h

    int t0   = dir ? (TT - 1) : 0;
    float xg = xp[(size_t)(t0 * BB + b) * 1024 + dir * GG + g];

    for (int s = 0; s < TT; s++) {
        // ---- phase 1: full dot for gate g ----
        // issue streamed octets 8..15 first (compiler pipelines them under
        // the LDS half)
        uint4 q8[8];
#pragma unroll
        for (int q = 0; q < 8; q++)
            q8[q] = wp[(q + 8) * GG + g];

        float acc = xg;             // xp term first (matches prior order)
        // octets 0..7 from LDS; h octet read is same-addr broadcast
#pragma unroll
        for (int q = 0; q < 8; q++) {
            uint4 w = wlds[q * GG + g];
            uint4 hv = h16v[q];
            acc = dot2h(w.x, hv.x, acc);
            acc = dot2h(w.y, hv.y, acc);
            acc = dot2h(w.z, hv.z, acc);
            acc = dot2h(w.w, hv.w, acc);
        }
        // octets 8..15 from L2 (preissued above)
#pragma unroll
        for (int q = 0; q < 8; q++) {
            uint4 w = q8[q];
            uint4 hv = h16v[q + 8];
            acc = dot2h(w.x, hv.x, acc);
            acc = dot2h(w.y, hv.y, acc);
            acc = dot2h(w.z, hv.z, acc);
            acc = dot2h(w.w, hv.w, acc);
        }

        // activate inline — no cross-thread reduction needed
        act[g] = (sect == 2) ? tanh_f(acc) : sigm_f(acc);

        // prefetch next step's xp while the barrier settles
        float xg_next = xg;
        if (s < TT - 1) {
            int tn = dir ? (TT - 2 - s) : (s + 1);
            xg_next = xp[(size_t)(tn * BB + b) * 1024 + dir * GG + g];
        }
        __syncthreads();

        // ---- phase 3: c/h update for hidden unit tid (<128) ----
        if (tid < HH) {
            float si = act[tid], sf = act[HH + tid];
            float tg = act[2 * HH + tid], so = act[3 * HH + tid];
            c = sf * c + si * tg;
            float h = so * tanh_f(c);
            h16_lds[tid] = __float2half(h);   // recurrence input (fp16)
            int t = dir ? (TT - 1 - s) : s;
            hout[((size_t)(dir * TT + t) * BB + b) * HH + tid] = h;  // fp32 out
        }
        xg = xg_next;
        __syncthreads();   // h16/act reuse vs next p1
    }
}

// ---------------------------------------------------------------------------
// Kernel 5: head — logits, softmax, argmax, chosen policy. One wave per row.
// ---------------------------------------------------------------------------
__global__ __launch_bounds__(256) void head_k(
    const float* __restrict__ hbuf,           // [2][T][B][H]
    const float* __restrict__ wout, const float* __restrict__ bout,
    float* __restrict__ out)
{
    int wid  = threadIdx.x >> 6;
    int lane = threadIdx.x & 63;
    int row  = blockIdx.x * 4 + wid;          // t*64+b, 0..8191
    int t = row >> 6, b = row & 63;
    const float* hf = hbuf + ((size_t)(t)      * BB + b) * HH;
    const float* hb = hbuf + ((size_t)(TT + t) * BB + b) * HH;

    float l0 = 0.f, l1 = 0.f, v;
    v = hf[lane];      l0 += v * wout[lane];           l1 += v * wout[256 + lane];
    v = hf[lane + 64]; l0 += v * wout[64 + lane];      l1 += v * wout[320 + lane];
    v = hb[lane];      l0 += v * wout[128 + lane];     l1 += v * wout[384 + lane];
    v = hb[lane + 64]; l0 += v * wout[192 + lane];     l1 += v * wout[448 + lane];
#pragma unroll
    for (int off = 32; off > 0; off >>= 1) {
        l0 += __shfl_down(l0, off);
        l1 += __shfl_down(l1, off);
    }
    if (lane == 0) {
        l0 += bout[0]; l1 += bout[1];
        float m  = fmaxf(l0, l1);
        float e0 = __expf(l0 - m), e1 = __expf(l1 - m);
        float inv = 1.f / (e0 + e1);
        float p0 = e0 * inv, p1 = e1 * inv;
        int amax = (l1 > l0) ? 1 : 0;          // tie -> 0, matches jnp.argmax
        out[(size_t)row * 2 + 0] = l0;
        out[(size_t)row * 2 + 1] = l1;
        out[16384 + (size_t)row * 2 + 0] = p0;
        out[16384 + (size_t)row * 2 + 1] = p1;
        out[32768 + row] = amax ? p1 : p0;
        out[40960 + row] = (float)amax;
    }
}

// ---------------------------------------------------------------------------
// Kernel 6: expand utterance mask to tokens, write masked input as float.
// ---------------------------------------------------------------------------
__global__ __launch_bounds__(256) void mask_k(
    const int* __restrict__ x, const int* __restrict__ seg,
    const float* __restrict__ umask, float* __restrict__ out4)
{
    int idx = blockIdx.x * 256 + threadIdx.x;    // < 131072
    int b = idx & 63;
    int s = seg[idx];
    if (s > TT - 1) s = TT - 1;                  // jnp OOB indexing clamps
    if (s < 0) s = 0;
    float keep = umask[s * BB + b];
    out4[idx] = (keep != 0.f) ? (float)x[idx] : 0.f;
}

// ---------------------------------------------------------------------------
extern "C" void kernel_launch(void* const* d_in, const int* in_sizes, int n_in,
                              void* d_out, int out_size, void* d_ws, size_t ws_size,
                              hipStream_t stream)
{
    const int*   x    = (const int*)  d_in[0];
    const float* emb  = (const float*)d_in[1];
    const float* wihf = (const float*)d_in[2];
    const float* whhf = (const float*)d_in[3];
    const float* bihf = (const float*)d_in[4];
    const float* bhhf = (const float*)d_in[5];
    const float* wihb = (const float*)d_in[6];
    const float* whhb = (const float*)d_in[7];
    const float* bihb = (const float*)d_in[8];
    const float* bhhb = (const float*)d_in[9];
    const float* wout = (const float*)d_in[10];
    const float* bout = (const float*)d_in[11];
    float* out = (float*)d_out;
    char*  ws  = (char*)d_ws;

    // workspace layout (bytes)
    int*   seg   = (int*)  (ws + 0);         // 2048*64*4   = 524288
    int*   cnt   = (int*)  (ws + 524288);    // 128*64*4    = 32768
    int*   start = (int*)  (ws + 557056);    // 32768
    float* up    = (float*)(ws + 589824);    // 128*64*256*4  = 8 MB
    float* xp    = (float*)(ws + 8978432);   // 128*64*1024*4 = 32 MB
    float* hbuf  = (float*)(ws + 42532864);  // 2*128*64*128*4 = 8 MB
    // fp16 weight copy lives in the first 256 KB of `up`, which is dead
    // after xp_gemm_k reads it (pool_k regenerates up each iteration).
    __half* wh16 = (__half*)up;

    segscan_k<<<64, 256, 0, stream>>>(x, seg, cnt, start);
    pool_k<<<2048, 256, 0, stream>>>(x, emb, cnt, start, up);   // 8192 waves
    xp_gemm_k<<<dim3(64, 8), 256, 0, stream>>>(up, wihf, wihb, bihf, bhhf, bihb, bhhb, xp);
    cvt_k<<<512, 256, 0, stream>>>(whhf, whhb, wh16);
    lstm_rec_k<<<128, 512, 0, stream>>>(xp, wh16, hbuf);
    head_k<<<2048, 256, 0, stream>>>(hbuf, wout, bout, out);
    mask_k<<<512, 256, 0, stream>>>(x, seg, out + 40960, out + 49152);
}

// Round 12
// 287.364 us; speedup vs baseline: 1.2440x; 1.0027x over previous
//
#include <hip/hip_runtime.h>
#include <hip/hip_fp16.h>
#include <math.h>

// Problem constants (from reference)
#define LL   2048     // seq len
#define BB   64       // batch
#define EE   256      // embedding
#define HH   128      // lstm hidden per dir
#define GG   512      // 4*H gates
#define TT   128      // utterances (L / SEP_EVERY)
#define SEPT 50256

// ---------------------------------------------------------------------------
// Kernel 1: per-column prefix-scan of SEP flags -> seg[t,b], plus per-(utt,b)
// token counts and start offsets (segments are contiguous per column).
// ---------------------------------------------------------------------------
__global__ __launch_bounds__(256) void segscan_k(
    const int* __restrict__ x, int* __restrict__ seg,
    int* __restrict__ cnt, int* __restrict__ start)
{
    int b   = blockIdx.x;    // 0..63
    int tid = threadIdx.x;   // 0..255, 8 tokens each
    __shared__ int tsum[256];
    __shared__ int ucnt[TT];
    __shared__ int ustart[TT];

    int flags[8];
    int local = 0;
#pragma unroll
    for (int i = 0; i < 8; i++) {
        int t = tid * 8 + i;
        flags[i] = (x[t * BB + b] == SEPT) ? 1 : 0;
        local += flags[i];
    }
    tsum[tid] = local;
    __syncthreads();
    int val = local;
    for (int off = 1; off < 256; off <<= 1) {
        int other = (tid >= off) ? tsum[tid - off] : 0;
        __syncthreads();
        val += other;
        tsum[tid] = val;
        __syncthreads();
    }
    int excl = val - local;   // seps strictly before this thread's chunk

    if (tid < TT) ucnt[tid] = 0;
    __syncthreads();
    int run = excl;
#pragma unroll
    for (int i = 0; i < 8; i++) {
        int t = tid * 8 + i;
        int s = run;                 // seg id = #seps before this token
        seg[t * BB + b] = s;
        run += flags[i];
        if (s < TT) atomicAdd(&ucnt[s], 1);
    }
    __syncthreads();
    if (tid == 0) {
        int acc = 0;
        for (int u = 0; u < TT; u++) { ustart[u] = acc; acc += ucnt[u]; }
    }
    __syncthreads();
    if (tid < TT) {
        cnt[tid * BB + b]   = ucnt[tid];
        start[tid * BB + b] = ustart[tid];
    }
}

// ---------------------------------------------------------------------------
// Kernel 2: embedding gather + mean pool. One WAVE per (utt,b); lane holds a
// float4 column slice -> one coalesced 1KB row read per token. Grid = 2048.
// ---------------------------------------------------------------------------
__global__ __launch_bounds__(256) void pool_k(
    const int* __restrict__ x, const float* __restrict__ emb,
    const int* __restrict__ cnt, const int* __restrict__ start,
    float* __restrict__ up)
{
    int wid  = threadIdx.x >> 6;
    int lane = threadIdx.x & 63;
    int bid  = blockIdx.x * 4 + wid;   // u*64+b, bid in [0,8192)
    int b    = bid & 63;
    int c    = cnt[bid];
    int st   = start[bid];

    float4 acc = {0.f, 0.f, 0.f, 0.f};
    int tok = (c > 0) ? x[st * BB + b] : 0;
    for (int j = 0; j < c; j++) {
        int tok_n = (j + 1 < c) ? x[(st + j + 1) * BB + b] : 0;  // prefetch
        float4 v = ((const float4*)(emb + (size_t)tok * EE))[lane];
        acc.x += v.x; acc.y += v.y; acc.z += v.z; acc.w += v.w;
        tok = tok_n;
    }
    float inv = (c > 0) ? 1.f / (float)c : 0.f;
    float4 r = {acc.x * inv, acc.y * inv, acc.z * inv, acc.w * inv};
    ((float4*)(up + (size_t)bid * EE))[lane] = r;
}

// ---------------------------------------------------------------------------
// Kernel 3: xp = u @ W_cat^T + (b_ih + b_hh).  fp32 register-tiled GEMM, v2.
// 128x128 tile, 256 threads, 8x8 micro-tile. Grid (64, 8) = 512 blocks.
// ---------------------------------------------------------------------------
__global__ __launch_bounds__(256) void xp_gemm_k(
    const float* __restrict__ A,
    const float* __restrict__ wf, const float* __restrict__ wb,
    const float* __restrict__ bihf, const float* __restrict__ bhhf,
    const float* __restrict__ bihb, const float* __restrict__ bhhb,
    float* __restrict__ C)
{
    __shared__ float As[32][128];   // [k][m] 16 KB
    __shared__ float Bs[32][128];   // [k][n] 16 KB
    int tid  = threadIdx.x;
    int row0 = blockIdx.x * 128;    // 64 blocks
    int col0 = blockIdx.y * 128;    // 8 blocks
    int tx = tid & 15, ty = tid >> 4;   // 16 x 16 threads, 8x8 micro
    float acc[8][8] = {};

    for (int k0 = 0; k0 < EE; k0 += 32) {
#pragma unroll
        for (int i = 0; i < 4; i++) {
            int idx = tid + i * 256;       // float4 slot, 1024 total
            int m   = idx >> 3;            // 0..127
            int k4  = idx & 7;             // 0..7
            float4 av = *(const float4*)(A + (size_t)(row0 + m) * EE + k0 + k4 * 4);
            As[k4 * 4 + 0][m] = av.x; As[k4 * 4 + 1][m] = av.y;
            As[k4 * 4 + 2][m] = av.z; As[k4 * 4 + 3][m] = av.w;
        }
#pragma unroll
        for (int i = 0; i < 4; i++) {
            int idx = tid + i * 256;
            int n   = idx >> 3;
            int k4  = idx & 7;
            int gc  = col0 + n;
            const float* wsrc = (gc < GG) ? (wf + (size_t)gc * EE)
                                          : (wb + (size_t)(gc - GG) * EE);
            float4 bv = *(const float4*)(wsrc + k0 + k4 * 4);
            Bs[k4 * 4 + 0][n] = bv.x; Bs[k4 * 4 + 1][n] = bv.y;
            Bs[k4 * 4 + 2][n] = bv.z; Bs[k4 * 4 + 3][n] = bv.w;
        }
        __syncthreads();
#pragma unroll
        for (int k = 0; k < 32; k++) {
            float a8[8], b8[8];
            *(float4*)&a8[0] = *(const float4*)&As[k][ty * 8 + 0];
            *(float4*)&a8[4] = *(const float4*)&As[k][ty * 8 + 4];
            *(float4*)&b8[0] = *(const float4*)&Bs[k][tx * 8 + 0];
            *(float4*)&b8[4] = *(const float4*)&Bs[k][tx * 8 + 4];
#pragma unroll
            for (int i = 0; i < 8; i++)
#pragma unroll
                for (int j = 0; j < 8; j++)
                    acc[i][j] += a8[i] * b8[j];
        }
        __syncthreads();
    }

    // epilogue: bias + float4 stores
    float bias[8];
#pragma unroll
    for (int j = 0; j < 8; j++) {
        int gc = col0 + tx * 8 + j;
        bias[j] = (gc < GG) ? (bihf[gc] + bhhf[gc])
                            : (bihb[gc - GG] + bhhb[gc - GG]);
    }
#pragma unroll
    for (int i = 0; i < 8; i++) {
        int r = row0 + ty * 8 + i;
        float4 v0 = {acc[i][0] + bias[0], acc[i][1] + bias[1],
                     acc[i][2] + bias[2], acc[i][3] + bias[3]};
        float4 v1 = {acc[i][4] + bias[4], acc[i][5] + bias[5],
                     acc[i][6] + bias[6], acc[i][7] + bias[7]};
        *(float4*)(C + (size_t)r * 1024 + col0 + tx * 8 + 0) = v0;
        *(float4*)(C + (size_t)r * 1024 + col0 + tx * 8 + 4) = v1;
    }
}

// ---------------------------------------------------------------------------
// Fast activations
// ---------------------------------------------------------------------------
__device__ __forceinline__ float sigm_f(float x) {
    return 1.f / (1.f + __expf(-x));
}
__device__ __forceinline__ float tanh_f(float x) {
    return 1.f - 2.f / (__expf(2.f * x) + 1.f);
}

// ---------------------------------------------------------------------------
// Kernel 3.5: convert W_hh (both dirs) to fp16 in octet-major layout:
// o[((dir*16+q)*512+g)*8+e] = whh[dir][g][q*8+e]   (q = k-octet 0..15)
// ---------------------------------------------------------------------------
__global__ __launch_bounds__(256) void cvt_k(
    const float* __restrict__ wf, const float* __restrict__ wb,
    __half* __restrict__ o)
{
    int i = blockIdx.x * 256 + threadIdx.x;   // 0..131071
    int e   = i & 7;
    int g   = (i >> 3) & 511;
    int q   = (i >> 12) & 15;
    int dir = i >> 16;
    const float* src = dir ? wb : wf;
    o[i] = __float2half(src[(size_t)g * HH + q * 8 + e]);
}

// v_dot2_f32_f16: c += a.x*b.x + a.y*b.y, fp16 inputs, fp32 accumulate.
typedef _Float16 h2v __attribute__((ext_vector_type(2)));
__device__ __forceinline__ float dot2h(unsigned wbits, unsigned hbits, float c) {
    return __builtin_amdgcn_fdot2(__builtin_bit_cast(h2v, wbits),
                                  __builtin_bit_cast(h2v, hbits), c, false);
}

// ---------------------------------------------------------------------------
// Kernel 4: LSTM recurrence — r23: r22 + REGISTER-HELD streamed octets.
//
// r22 post-mortem (98.5 us, VGPR 52): one-gate-per-thread killed the
// phase-2 reduction (113 -> 98.5), but the 8 streamed octets were NOT
// held — the compiler re-sinks the loop-invariant wp[] loads into the dot
// chain with ~2-3 in flight -> ~3 serialized L2 round trips (~600 cyc)
// exposed per step.
//
// r23: the streamed octets are LOOP-INVARIANT (same 128 B/thread every
// step). Load them ONCE before the loop with plain compiler-scheduled
// loads (the style that works), then one-time opaque empty-asm
// ("+v") copies: non-rematerializable, so the RA must either allocate
// them (demand ~84 < 128 cap — unlike the 64-128-reg attempts r12-r16)
// or scratch-spill (neutral: scratch is L2-backed ~= today's stream; no
// r14-style address-recompute serialization since values, not pointers,
// are pinned). Win case: zero per-step L2 traffic, feed floor = LDS port
// ~512 cyc.
// Sum order unchanged from r22 -> absmax identical 0.00195.
// Predicted: VGPR 52 -> ~84-100 (tell); lstm 98.5 -> 70-85 us.
// Pre-commit: VGPR<=60 AND dur>=95 -> lstm at toolchain floor, pivot to
// xp_gemm/pool next.
// ---------------------------------------------------------------------------
__global__ __launch_bounds__(512, 2) void lstm_rec_k(
    const float* __restrict__ xp,            // [T*B][1024]
    const __half* __restrict__ w16,          // [dir][q][gate][8] octet-major
    float* __restrict__ hout)                // [2][T][B][H]
{
    int bid = blockIdx.x;
    int dir = bid >> 6;
    int b   = bid & 63;
    int tid = threadIdx.x;
    int g   = tid;                  // this thread's gate
    int sect = g >> 7;              // 0:i 1:f 2:g 3:o (wave-uniform)
    const uint4* wp = (const uint4*)(w16 + (size_t)dir * (16 * GG * 8));

    __shared__ uint4 wlds[8 * GG];            // octets 0..7, 64 KB, [q][g]
    __shared__ __align__(16) __half h16_lds[HH];
    __shared__ float act[GG];

    // one-time stage: 64 KB (coalesced: consecutive tids -> consecutive uint4)
#pragma unroll
    for (int t = 0; t < 8; t++) {
        int idx = tid + t * 512;    // = q*512 + g for q=0..7
        wlds[idx] = wp[idx];
    }

    // one-time load of streamed octets 8..15 (loop-invariant), then opaque
    // copy so the RA cannot re-sink them into the loop.
    uint4 q8[8];
#pragma unroll
    for (int q = 0; q < 8; q++)
        q8[q] = wp[(q + 8) * GG + g];
#pragma unroll
    for (int q = 0; q < 8; q++) {
        asm volatile("" : "+v"(q8[q].x), "+v"(q8[q].y),
                          "+v"(q8[q].z), "+v"(q8[q].w));
    }

    float c = 0.f;                  // cell state (threads < 128)
    if (tid < HH) h16_lds[tid] = __float2half(0.f);
    __syncthreads();

    const uint4* h16v = (const uint4*)h16_lds;   // 16 octets of h

    int t0   = dir ? (TT - 1) : 0;
    float xg = xp[(size_t)(t0 * BB + b) * 1024 + dir * GG + g];

    for (int s = 0; s < TT; s++) {
        // ---- phase 1: full dot for gate g ----
        float acc = xg;             // xp term first (matches prior order)
        // octets 0..7 from LDS; h octet read is same-addr broadcast
#pragma unroll
        for (int q = 0; q < 8; q++) {
            uint4 w = wlds[q * GG + g];
            uint4 hv = h16v[q];
            acc = dot2h(w.x, hv.x, acc);
            acc = dot2h(w.y, hv.y, acc);
            acc = dot2h(w.z, hv.z, acc);
            acc = dot2h(w.w, hv.w, acc);
        }
        // octets 8..15 from registers (held across the loop)
#pragma unroll
        for (int q = 0; q < 8; q++) {
            uint4 w = q8[q];
            uint4 hv = h16v[q + 8];
            acc = dot2h(w.x, hv.x, acc);
            acc = dot2h(w.y, hv.y, acc);
            acc = dot2h(w.z, hv.z, acc);
            acc = dot2h(w.w, hv.w, acc);
        }

        // activate inline — no cross-thread reduction needed
        act[g] = (sect == 2) ? tanh_f(acc) : sigm_f(acc);

        // prefetch next step's xp while the barrier settles
        float xg_next = xg;
        if (s < TT - 1) {
            int tn = dir ? (TT - 2 - s) : (s + 1);
            xg_next = xp[(size_t)(tn * BB + b) * 1024 + dir * GG + g];
        }
        __syncthreads();

        // ---- phase 3: c/h update for hidden unit tid (<128) ----
        if (tid < HH) {
            float si = act[tid], sf = act[HH + tid];
            float tg = act[2 * HH + tid], so = act[3 * HH + tid];
            c = sf * c + si * tg;
            float h = so * tanh_f(c);
            h16_lds[tid] = __float2half(h);   // recurrence input (fp16)
            int t = dir ? (TT - 1 - s) : s;
            hout[((size_t)(dir * TT + t) * BB + b) * HH + tid] = h;  // fp32 out
        }
        xg = xg_next;
        __syncthreads();   // h16/act reuse vs next p1
    }
}

// ---------------------------------------------------------------------------
// Kernel 5: head — logits, softmax, argmax, chosen policy. One wave per row.
// ---------------------------------------------------------------------------
__global__ __launch_bounds__(256) void head_k(
    const float* __restrict__ hbuf,           // [2][T][B][H]
    const float* __restrict__ wout, const float* __restrict__ bout,
    float* __restrict__ out)
{
    int wid  = threadIdx.x >> 6;
    int lane = threadIdx.x & 63;
    int row  = blockIdx.x * 4 + wid;          // t*64+b, 0..8191
    int t = row >> 6, b = row & 63;
    const float* hf = hbuf + ((size_t)(t)      * BB + b) * HH;
    const float* hb = hbuf + ((size_t)(TT + t) * BB + b) * HH;

    float l0 = 0.f, l1 = 0.f, v;
    v = hf[lane];      l0 += v * wout[lane];           l1 += v * wout[256 + lane];
    v = hf[lane + 64]; l0 += v * wout[64 + lane];      l1 += v * wout[320 + lane];
    v = hb[lane];      l0 += v * wout[128 + lane];     l1 += v * wout[384 + lane];
    v = hb[lane + 64]; l0 += v * wout[192 + lane];     l1 += v * wout[448 + lane];
#pragma unroll
    for (int off = 32; off > 0; off >>= 1) {
        l0 += __shfl_down(l0, off);
        l1 += __shfl_down(l1, off);
    }
    if (lane == 0) {
        l0 += bout[0]; l1 += bout[1];
        float m  = fmaxf(l0, l1);
        float e0 = __expf(l0 - m), e1 = __expf(l1 - m);
        float inv = 1.f / (e0 + e1);
        float p0 = e0 * inv, p1 = e1 * inv;
        int amax = (l1 > l0) ? 1 : 0;          // tie -> 0, matches jnp.argmax
        out[(size_t)row * 2 + 0] = l0;
        out[(size_t)row * 2 + 1] = l1;
        out[16384 + (size_t)row * 2 + 0] = p0;
        out[16384 + (size_t)row * 2 + 1] = p1;
        out[32768 + row] = amax ? p1 : p0;
        out[40960 + row] = (float)amax;
    }
}

// ---------------------------------------------------------------------------
// Kernel 6: expand utterance mask to tokens, write masked input as float.
// ---------------------------------------------------------------------------
__global__ __launch_bounds__(256) void mask_k(
    const int* __restrict__ x, const int* __restrict__ seg,
    const float* __restrict__ umask, float* __restrict__ out4)
{
    int idx = blockIdx.x * 256 + threadIdx.x;    // < 131072
    int b = idx & 63;
    int s = seg[idx];
    if (s > TT - 1) s = TT - 1;                  // jnp OOB indexing clamps
    if (s < 0) s = 0;
    float keep = umask[s * BB + b];
    out4[idx] = (keep != 0.f) ? (float)x[idx] : 0.f;
}

// ---------------------------------------------------------------------------
extern "C" void kernel_launch(void* const* d_in, const int* in_sizes, int n_in,
                              void* d_out, int out_size, void* d_ws, size_t ws_size,
                              hipStream_t stream)
{
    const int*   x    = (const int*)  d_in[0];
    const float* emb  = (const float*)d_in[1];
    const float* wihf = (const float*)d_in[2];
    const float* whhf = (const float*)d_in[3];
    const float* bihf = (const float*)d_in[4];
    const float* bhhf = (const float*)d_in[5];
    const float* wihb = (const float*)d_in[6];
    const float* whhb = (const float*)d_in[7];
    const float* bihb = (const float*)d_in[8];
    const float* bhhb = (const float*)d_in[9];
    const float* wout = (const float*)d_in[10];
    const float* bout = (const float*)d_in[11];
    float* out = (float*)d_out;
    char*  ws  = (char*)d_ws;

    // workspace layout (bytes)
    int*   seg   = (int*)  (ws + 0);         // 2048*64*4   = 524288
    int*   cnt   = (int*)  (ws + 524288);    // 128*64*4    = 32768
    int*   start = (int*)  (ws + 557056);    // 32768
    float* up    = (float*)(ws + 589824);    // 128*64*256*4  = 8 MB
    float* xp    = (float*)(ws + 8978432);   // 128*64*1024*4 = 32 MB
    float* hbuf  = (float*)(ws + 42532864);  // 2*128*64*128*4 = 8 MB
    // fp16 weight copy lives in the first 256 KB of `up`, which is dead
    // after xp_gemm_k reads it (pool_k regenerates up each iteration).
    __half* wh16 = (__half*)up;

    segscan_k<<<64, 256, 0, stream>>>(x, seg, cnt, start);
    pool_k<<<2048, 256, 0, stream>>>(x, emb, cnt, start, up);   // 8192 waves
    xp_gemm_k<<<dim3(64, 8), 256, 0, stream>>>(up, wihf, wihb, bihf, bhhf, bihb, bhhb, xp);
    cvt_k<<<512, 256, 0, stream>>>(whhf, whhb, wh16);
    lstm_rec_k<<<128, 512, 0, stream>>>(xp, wh16, hbuf);
    head_k<<<2048, 256, 0, stream>>>(hbuf, wout, bout, out);
    mask_k<<<512, 256, 0, stream>>>(x, seg, out + 40960, out + 49152);
}